// Round 8
// baseline (318.288 us; speedup 1.0000x reference)
//
#include <hip/hip_runtime.h>
#include <math.h>

#define NB 16384
#define NTOK 128
#define NKEY 2662           // 22*11*11
#define NLOG 19
#define TB 16               // batches per workgroup in main kernel

typedef __attribute__((ext_vector_type(8))) short short8;
typedef __attribute__((ext_vector_type(4))) float floatx4;

struct Tok3 { int x, y, z; };

__device__ __constant__ float c_maxv[22] = {
    9.f, 1.f, 1.f, 10.f, 3.f, 254.f, 1.f, 1.f, 235.f, 8.f, 9.f, 250.f,
    29.f, 1.f, 1.f, 8.f, 1.f, 1.f, 6.f, 3.f, 1.f, 2.f};

__device__ __forceinline__ unsigned short f2bf(float f) {
    unsigned u = __float_as_uint(f);
    return (unsigned short)((u + 0x7FFFu + ((u >> 16) & 1u)) >> 16);  // RNE
}
__device__ __forceinline__ float tanh_fast(float x) {
    float e = __builtin_amdgcn_exp2f(x * 2.885390082f);   // 2*log2(e)
    return 1.f - 2.f * __builtin_amdgcn_rcpf(e + 1.f);
}

// ---------------------------------------------------------------------------
// Precompute A: W2Ft[uk][p] = sum_v fc1w[p][v]*w2[v][uk]  (576x128),
// encwT, beff/blog chain, Wlog, c1wb(bf16).  Grid = 107 WGs.
// ---------------------------------------------------------------------------
__global__ __launch_bounds__(256) void k_preA(
    const float* __restrict__ w1, const float* __restrict__ b1,
    const float* __restrict__ w2, const float* __restrict__ b2,
    const float* __restrict__ fc1w, const float* __restrict__ fc1b,
    const float* __restrict__ encw, const float* __restrict__ encb,
    const float* __restrict__ a1w, const float* __restrict__ a1b,
    const float* __restrict__ aemb,
    const float* __restrict__ h0w, const float* __restrict__ h0b,
    const float* __restrict__ h1w, const float* __restrict__ h1b,
    const float* __restrict__ c1w,
    float* __restrict__ W2Ft, float* __restrict__ encwT,
    float* __restrict__ beff, float* __restrict__ blog,
    float* __restrict__ Wlog, unsigned short* __restrict__ c1wb)
{
    __shared__ float sF[64 * 129];        // 33 KB (fc1w^T staged, pad 129)
    const int bid = blockIdx.x, t = threadIdx.x;

    if (bid < 72) {
        // ---- W2Ft: 8 uk rows per WG ----
        #pragma unroll
        for (int r = 0; r < 32; ++r) {    // stage fc1w^T: sF[v][p]
            int idx = t + 256 * r;        // 8192 = 128p x 64v
            int p_ = idx >> 6, v_ = idx & 63;
            sF[v_ * 129 + p_] = fc1w[idx];
        }
        __syncthreads();
        #pragma unroll
        for (int r = 0; r < 4; ++r) {
            int idx = t + 256 * r;        // 1024 = 8 ukl x 128 p
            int p = idx & 127;
            int uk = __builtin_amdgcn_readfirstlane(bid * 8 + (idx >> 7));
            float acc = 0.f;
            #pragma unroll 8
            for (int v = 0; v < 64; ++v)
                acc += sF[v * 129 + p] * w2[v * 576 + uk];
            W2Ft[uk * 128 + p] = acc;
        }
    } else if (bid == 72) {
        // ---- chain: h2b -> s_t -> beff; emb -> blog ----
        float* s_part = sF;          // [4*64]
        float* s_h2b  = sF + 256;    // [64]
        float* s_emb  = sF + 320;    // [16]
        float* s_t    = sF + 336;    // [128]
        {   // 4-way split of the w2 gather
            int v = t & 63, part = t >> 6;
            float s = 0.f;
            for (int u = part * 16; u < part * 16 + 16; ++u) {
                float ws = 0.f;
                #pragma unroll
                for (int k = 0; k < 9; ++k) ws += w2[v * 576 + u * 9 + k];
                s += b1[u] * ws;
            }
            s_part[part * 64 + v] = s;
        }
        if (t < 16) {
            float s = 0.f;
            for (int r = 0; r < 100; ++r) s += aemb[r * 16 + t];
            s_emb[t] = s * 0.01f;
        }
        __syncthreads();
        if (t < 64)
            s_h2b[t] = b2[t] + s_part[t] + s_part[64 + t] + s_part[128 + t] + s_part[192 + t];
        __syncthreads();
        if (t < 128) {
            float s = fc1b[t];
            for (int v = 0; v < 64; ++v) s += fc1w[t * 64 + v] * s_h2b[v];
            s_t[t] = s;
        }
        __syncthreads();
        if (t < 128) {
            float s = encb[t];
            for (int p = 0; p < 128; ++p) s += encw[t * 128 + p] * s_t[p];
            beff[t] = s;
        } else if (t < 128 + NLOG) {
            int o = t - 128;
            float s = (o < 9) ? h0b[o] : h1b[o - 9];
            for (int a = 0; a < 512; ++a) {
                float hw = (o < 9) ? h0w[o * 528 + a] : h1w[(o - 9) * 528 + a];
                s += hw * a1b[a];
            }
            for (int e = 0; e < 16; ++e) {
                float hw = (o < 9) ? h0w[o * 528 + 512 + e] : h1w[(o - 9) * 528 + 512 + e];
                s += hw * s_emb[e];
            }
            blog[o] = s;
        }
    } else if (bid < 83) {
        // ---- Wlog[o][h] = sum_a headW[o][a] * actor1_w[a][h] ----
        int n = (bid - 73) * 256 + t;
        if (n < NLOG * 128) {
            int o = __builtin_amdgcn_readfirstlane(n >> 7);
            int h = n & 127;
            const float* hw = (o < 9) ? (h0w + o * 528) : (h1w + (o - 9) * 528);
            float acc = 0.f;
            #pragma unroll 8
            for (int a = 0; a < 512; ++a)
                acc += hw[a] * a1w[a * 128 + h];
            Wlog[n] = acc;
        }
    } else if (bid < 99) {
        // ---- c1wb bf16 convert, same [j][k] layout (B^T for MFMA) ----
        #pragma unroll
        for (int r = 0; r < 32; ++r) {
            int n = (bid - 83) * 8192 + t + 256 * r;   // 16*8192 = 131072
            c1wb[n] = f2bf(c1w[n]);
        }
    } else {
        // ---- encwT[p][h] = encw[h][p] ----
        #pragma unroll
        for (int r = 0; r < 8; ++r) {
            int idx = (bid - 99) * 2048 + t + 256 * r; // 8*2048 = 16384
            int h = idx >> 7, p = idx & 127;
            encwT[p * 128 + h] = encw[idx];
        }
    }
}

// ---------------------------------------------------------------------------
// Precompute B: Weff[key][h] (1/MAX folded). Grid = 1331 WGs, 2 keys each.
// ---------------------------------------------------------------------------
__global__ __launch_bounds__(256) void k_preB(
    const float* __restrict__ W2Ft, const float* __restrict__ w1,
    const float* __restrict__ encwT, float* __restrict__ Weff)
{
    __shared__ float sA[2][128];
    const int t = threadIdx.x, bid = blockIdx.x;
    const int half = t >> 7, p = t & 127;
    const int key = __builtin_amdgcn_readfirstlane(bid * 2 + half);
    const int c = key / 121, rem = key % 121, X = rem / 11, Y = rem % 11;

    float acc = 0.f;
    for (int u = 0; u < 64; ++u) {
        const float* w1u = w1 + u * 550 + c * 25;
        #pragma unroll
        for (int i = 0; i < 3; ++i) {
            int xi = X - 3 * i;
            if (xi < 0 || xi > 4) continue;       // wave-uniform
            #pragma unroll
            for (int j = 0; j < 3; ++j) {
                int yj = Y - 3 * j;
                if (yj < 0 || yj > 4) continue;   // wave-uniform
                acc += w1u[xi * 5 + yj] * W2Ft[(u * 9 + i * 3 + j) * 128 + p];
            }
        }
    }
    sA[half][p] = acc / c_maxv[c];
    __syncthreads();

    float o = 0.f;
    #pragma unroll 8
    for (int p2 = 0; p2 < 128; ++p2)
        o += encwT[p2 * 128 + p] * sA[half][p2];
    Weff[key * 128 + p] = o;
}

// ---------------------------------------------------------------------------
// Main fused kernel. Grid = 1024 batch-blocks x 4 j-blocks = 4096 WGs,
// 256 threads, TB=16 (full M=16 MFMA tile). Each WG covers 256 j; value
// partials go to workspace (deterministic, no atomics); jb==0 WGs also
// write the logits.
// ---------------------------------------------------------------------------
__global__ __launch_bounds__(256) void k_main(
    const int* __restrict__ obs,
    const float* __restrict__ Weff, const float* __restrict__ beff,
    const unsigned short* __restrict__ c1wb, const float* __restrict__ c1b,
    const float* __restrict__ vw,
    const float* __restrict__ Wlog, const float* __restrict__ blog,
    float* __restrict__ vpartial, float* __restrict__ out)
{
    __shared__ int            s_lst[TB * 32];      // 2 KB packed token list
    __shared__ float          s_hidden[TB * 128];  // 8 KB fp32 (for logits)
    __shared__ unsigned short s_hb[16 * 136];      // 4.25 KB bf16, pad 136
    __shared__ int            s_cnt[TB];
    __shared__ float          s_val[64];

    const int tid = threadIdx.x, bid = blockIdx.x;
    const int jb = bid & 3;                        // j-block: 256 j each
    const int b0 = (bid >> 2) * TB;

    if (tid < TB) s_cnt[tid] = 0;
    __syncthreads();

    // ---- Phase A: decode + append valid tokens (pack m<<20|val<<12|key) ----
    {
        const Tok3* obs3 = (const Tok3*)obs;
        const int gtok0 = b0 * NTOK;
        #pragma unroll
        for (int k = 0; k < TB * NTOK / 256; ++k) {
            int tt = tid + 256 * k;                // tt = bb*128 + m
            Tok3 o = obs3[gtok0 + tt];
            int o0 = (o.x == 255) ? 0 : o.x;       // per-component 255 masking
            int o1 = (o.y == 255) ? 0 : o.y;
            int o2 = (o.z == 255) ? 0 : o.z;
            int x = (o0 >> 4) & 15, y = o0 & 15;
            if (x < 11 && y < 11 && o1 < 22) {
                int bb = tt >> 7, m = tt & 127;
                int pos = atomicAdd(&s_cnt[bb], 1);
                if (pos < 32)
                    s_lst[bb * 32 + pos] = (m << 20) | (o2 << 12) | (o1 * 121 + x * 11 + y);
            }
        }
    }
    __syncthreads();

    // ---- Phase A2: last-write-wins dedupe on the tiny list ----
    {
        int bb = tid >> 4, e0 = tid & 15;
        int n = s_cnt[bb]; if (n > 32) n = 32;
        #pragma unroll
        for (int r = 0; r < 2; ++r) {
            int e = e0 + 16 * r;
            if (e < n) {
                int p = s_lst[bb * 32 + e];
                bool dead = false;
                for (int i = 0; i < n; ++i) {
                    int q = s_lst[bb * 32 + i];
                    dead |= (((q ^ p) & 0xFFF) == 0) && (q > p);
                }
                if (dead) s_lst[bb * 32 + e] = p & ~0x000FF000;  // val := 0
            }
        }
    }
    __syncthreads();

    // ---- Phase B: hidden[b][h] = b_eff[h] + sum val * Weff[key][h] ----
    {
        int h = tid & 127, bg = tid >> 7;
        for (int bb = bg; bb < TB; bb += 2) {
            float acc = beff[h];
            int n = s_cnt[bb]; if (n > 32) n = 32;
            for (int i = 0; i < n; ++i) {
                int p = s_lst[bb * 32 + i];
                acc += (float)((p >> 12) & 0xFF) * Weff[(p & 0xFFF) * 128 + h];
            }
            s_hidden[bb * 128 + h] = acc;
            s_hb[bb * 136 + h] = f2bf(acc);
        }
    }
    __syncthreads();

    // ---- Phase C: value partial over this WG's 256 j  (bf16 MFMA) ----
    {
        const int lane = tid & 63, w = tid >> 6;
        const int lm = lane & 15, quad = lane >> 4;
        short8 af[4];
        #pragma unroll
        for (int kk = 0; kk < 4; ++kk)
            af[kk] = *(const short8*)&s_hb[lm * 136 + kk * 32 + quad * 8];

        float vpart[4] = {0.f, 0.f, 0.f, 0.f};
        #pragma unroll
        for (int nt = 0; nt < 4; ++nt) {           // 4 n-tiles of 16 j
            int j = jb * 256 + w * 64 + nt * 16 + lm;
            floatx4 acc = {0.f, 0.f, 0.f, 0.f};
            #pragma unroll
            for (int kk = 0; kk < 4; ++kk) {
                short8 bf = *(const short8*)&c1wb[j * 128 + kk * 32 + quad * 8];
                acc = __builtin_amdgcn_mfma_f32_16x16x32_bf16(af[kk], bf, acc, 0, 0, 0);
            }
            float bj = c1b[j], wj = vw[j];
            #pragma unroll
            for (int r = 0; r < 4; ++r)            // rows m = quad*4+r
                vpart[r] += tanh_fast(acc[r] + bj) * wj;
        }
        #pragma unroll
        for (int off = 1; off <= 8; off <<= 1)     // reduce over 16 cols
            #pragma unroll
            for (int r = 0; r < 4; ++r)
                vpart[r] += __shfl_xor(vpart[r], off, 64);
        if (lm == 0) {
            #pragma unroll
            for (int r = 0; r < 4; ++r)
                s_val[w * 16 + quad * 4 + r] = vpart[r];
        }
    }
    __syncthreads();
    if (tid < TB) {
        float v = s_val[tid] + s_val[16 + tid] + s_val[32 + tid] + s_val[48 + tid];
        vpartial[jb * NB + b0 + tid] = v;          // deterministic, no atomics
    }

    // ---- Phase D: logits (jb==0 WGs only) ----
    if (jb == 0) {
        const float4* s_h4 = (const float4*)s_hidden;
        const float4* wl4  = (const float4*)Wlog;
        int bl = tid >> 4, oo = tid & 15;
        #pragma unroll
        for (int rep = 0; rep < 2; ++rep) {
            int o = oo + rep * 16;
            if (o < NLOG) {
                float acc = blog[o];
                #pragma unroll
                for (int hq = 0; hq < 32; ++hq) {
                    float4 hv = s_h4[bl * 32 + hq];
                    float4 wl = wl4[o * 32 + hq];
                    acc += wl.x * hv.x + wl.y * hv.y + wl.z * hv.z + wl.w * hv.w;
                }
                out[(b0 + bl) * NLOG + o] = acc;
            }
        }
    }
}

// ---------------------------------------------------------------------------
// Final: value[b] = vb + sum over 4 j-block partials. Grid = 64 WGs.
// ---------------------------------------------------------------------------
__global__ __launch_bounds__(256) void k_fin(
    const float* __restrict__ vpartial, const float* __restrict__ vb,
    float* __restrict__ out)
{
    int i = blockIdx.x * 256 + threadIdx.x;        // 64*256 = 16384 exact
    out[NB * NLOG + i] = vb[0] + vpartial[i] + vpartial[NB + i]
                       + vpartial[2 * NB + i] + vpartial[3 * NB + i];
}

// ---------------------------------------------------------------------------
extern "C" void kernel_launch(void* const* d_in, const int* in_sizes, int n_in,
                              void* d_out, int out_size, void* d_ws, size_t ws_size,
                              hipStream_t stream)
{
    const int*   obs  = (const int*)  d_in[0];
    const float* w1   = (const float*)d_in[1];
    const float* b1   = (const float*)d_in[2];
    const float* w2   = (const float*)d_in[3];
    const float* b2   = (const float*)d_in[4];
    const float* fc1w = (const float*)d_in[5];
    const float* fc1b = (const float*)d_in[6];
    const float* encw = (const float*)d_in[7];
    const float* encb = (const float*)d_in[8];
    const float* c1w  = (const float*)d_in[9];
    const float* c1b  = (const float*)d_in[10];
    const float* vw   = (const float*)d_in[11];
    const float* vb   = (const float*)d_in[12];
    const float* a1w  = (const float*)d_in[13];
    const float* a1b  = (const float*)d_in[14];
    const float* aemb = (const float*)d_in[15];
    const float* h0w  = (const float*)d_in[16];
    const float* h0b  = (const float*)d_in[17];
    const float* h1w  = (const float*)d_in[18];
    const float* h1b  = (const float*)d_in[19];

    float* W     = (float*)d_ws;
    float* W2Ft  = W;                 // 73728  (576 x 128)
    float* encwT = W + 73728;         // 16384
    float* beff  = W + 90112;         // 128
    float* blog  = W + 90240;         // 32
    float* Wlog  = W + 90272;         // 2432
    float* Weff  = W + 92704;         // 340736
    unsigned short* c1wb = (unsigned short*)(W + 433440);  // 131072 ushort (=65536 f)
    float* vpart = W + 498976;        // 65536  (4 x NB)   total ~2.26 MB

    hipLaunchKernelGGL(k_preA, dim3(107), dim3(256), 0, stream,
                       w1, b1, w2, b2, fc1w, fc1b, encw, encb, a1w, a1b, aemb,
                       h0w, h0b, h1w, h1b, c1w,
                       W2Ft, encwT, beff, blog, Wlog, c1wb);
    hipLaunchKernelGGL(k_preB, dim3(1331), dim3(256), 0, stream,
                       W2Ft, w1, encwT, Weff);
    hipLaunchKernelGGL(k_main, dim3(4096), dim3(256), 0, stream,
                       obs, Weff, beff, c1wb, c1b, vw, Wlog, blog,
                       vpart, (float*)d_out);
    hipLaunchKernelGGL(k_fin, dim3(64), dim3(256), 0, stream,
                       vpart, vb, (float*)d_out);
}

// Round 10
// 211.824 us; speedup vs baseline: 1.5026x; 1.5026x over previous
//
#include <hip/hip_runtime.h>
#include <math.h>

#define NB 16384
#define NTOK 128
#define NKEY 2662           // 22*11*11
#define NLOG 19
#define TB 8                // batches per workgroup in k_hidden

typedef __attribute__((ext_vector_type(8))) short short8;
typedef __attribute__((ext_vector_type(4))) float floatx4;

struct Tok3 { int x, y, z; };

__device__ __constant__ float c_maxv[22] = {
    9.f, 1.f, 1.f, 10.f, 3.f, 254.f, 1.f, 1.f, 235.f, 8.f, 9.f, 250.f,
    29.f, 1.f, 1.f, 8.f, 1.f, 1.f, 6.f, 3.f, 1.f, 2.f};

__device__ __forceinline__ unsigned short f2bf(float f) {
    unsigned u = __float_as_uint(f);
    return (unsigned short)((u + 0x7FFFu + ((u >> 16) & 1u)) >> 16);  // RNE
}
__device__ __forceinline__ float tanh_fast(float x) {
    float e = __builtin_amdgcn_exp2f(x * 2.885390082f);   // 2*log2(e)
    return 1.f - 2.f * __builtin_amdgcn_rcpf(e + 1.f);
}

// ---------------------------------------------------------------------------
// Precompute A. Grid = 109 WGs:
//   0..71  W2Ft[uk][p] = sum_v fc1w[p][v]*w2[v][uk]
//   72     h2b -> beff chain
//   73     blog (parallelized 19x13 partials)
//   74..84 Wlog
//   85..100 c1wb bf16
//   101..108 encwT
// ---------------------------------------------------------------------------
__global__ __launch_bounds__(256) void k_preA(
    const float* __restrict__ w1, const float* __restrict__ b1,
    const float* __restrict__ w2, const float* __restrict__ b2,
    const float* __restrict__ fc1w, const float* __restrict__ fc1b,
    const float* __restrict__ encw, const float* __restrict__ encb,
    const float* __restrict__ a1w, const float* __restrict__ a1b,
    const float* __restrict__ aemb,
    const float* __restrict__ h0w, const float* __restrict__ h0b,
    const float* __restrict__ h1w, const float* __restrict__ h1b,
    const float* __restrict__ c1w,
    float* __restrict__ W2Ft, float* __restrict__ encwT,
    float* __restrict__ beff, float* __restrict__ blog,
    float* __restrict__ Wlog, unsigned short* __restrict__ c1wb)
{
    __shared__ float sF[64 * 129];        // 33 KB
    const int bid = blockIdx.x, t = threadIdx.x;

    if (bid < 72) {
        // ---- W2Ft: 8 uk rows per WG ----
        #pragma unroll
        for (int r = 0; r < 32; ++r) {    // stage fc1w^T: sF[v][p]
            int idx = t + 256 * r;        // 8192 = 128p x 64v
            int p_ = idx >> 6, v_ = idx & 63;
            sF[v_ * 129 + p_] = fc1w[idx];
        }
        __syncthreads();
        #pragma unroll
        for (int r = 0; r < 4; ++r) {
            int idx = t + 256 * r;
            int p = idx & 127;
            int uk = __builtin_amdgcn_readfirstlane(bid * 8 + (idx >> 7));
            float acc = 0.f;
            #pragma unroll 8
            for (int v = 0; v < 64; ++v)
                acc += sF[v * 129 + p] * w2[v * 576 + uk];
            W2Ft[uk * 128 + p] = acc;
        }
    } else if (bid == 72) {
        // ---- chain: h2b -> s_t -> beff ----
        float* s_part = sF;          // [4*64]
        float* s_h2b  = sF + 256;    // [64]
        float* s_t    = sF + 320;    // [128]
        {   // 4-way split of the w2 gather
            int v = t & 63, part = t >> 6;
            float s = 0.f;
            for (int u = part * 16; u < part * 16 + 16; ++u) {
                float ws = 0.f;
                #pragma unroll
                for (int k = 0; k < 9; ++k) ws += w2[v * 576 + u * 9 + k];
                s += b1[u] * ws;
            }
            s_part[part * 64 + v] = s;
        }
        __syncthreads();
        if (t < 64)
            s_h2b[t] = b2[t] + s_part[t] + s_part[64 + t] + s_part[128 + t] + s_part[192 + t];
        __syncthreads();
        if (t < 128) {
            float s = fc1b[t];
            for (int v = 0; v < 64; ++v) s += fc1w[t * 64 + v] * s_h2b[v];
            s_t[t] = s;
        }
        __syncthreads();
        if (t < 128) {
            float s = encb[t];
            for (int p = 0; p < 128; ++p) s += encw[t * 128 + p] * s_t[p];
            beff[t] = s;
        }
    } else if (bid == 73) {
        // ---- blog[o] = head_b[o] + headW[o][0:512].a1b + headW[o][512:528].emb
        float* s_cat = sF;            // [528] = cat(a1b, emb)
        float* s_p   = sF + 528;      // [19*13]
        if (t < 16) {
            float s = 0.f;
            for (int r = 0; r < 100; ++r) s += aemb[r * 16 + t];
            s_cat[512 + t] = s * 0.01f;
        } else if (t >= 64 && t < 64 + 128) {
            s_cat[t - 64] = a1b[t - 64];
            s_cat[t - 64 + 128] = a1b[t - 64 + 128];
            s_cat[t - 64 + 256] = a1b[t - 64 + 256];
            s_cat[t - 64 + 384] = a1b[t - 64 + 384];
        }
        __syncthreads();
        if (t < 247) {
            int o = t / 13, ch = t % 13;
            const float* hw = (o < 9) ? (h0w + o * 528) : (h1w + (o - 9) * 528);
            int i0 = ch * 41, i1 = i0 + 41; if (i1 > 528) i1 = 528;
            float s = 0.f;
            for (int i = i0; i < i1; ++i) s += hw[i] * s_cat[i];
            s_p[t] = s;
        }
        __syncthreads();
        if (t < NLOG) {
            float s = (t < 9) ? h0b[t] : h1b[t - 9];
            #pragma unroll
            for (int ch = 0; ch < 13; ++ch) s += s_p[t * 13 + ch];
            blog[t] = s;
        }
    } else if (bid < 85) {
        // ---- Wlog[o][h] = sum_a headW[o][a] * actor1_w[a][h] ----
        int n = (bid - 74) * 256 + t;
        if (n < NLOG * 128) {
            int o = __builtin_amdgcn_readfirstlane(n >> 7);
            int h = n & 127;
            const float* hw = (o < 9) ? (h0w + o * 528) : (h1w + (o - 9) * 528);
            float acc = 0.f;
            #pragma unroll 8
            for (int a = 0; a < 512; ++a)
                acc += hw[a] * a1w[a * 128 + h];
            Wlog[n] = acc;
        }
    } else if (bid < 101) {
        // ---- c1wb bf16 convert, [j][k] layout (B^T for MFMA) ----
        #pragma unroll
        for (int r = 0; r < 32; ++r) {
            int n = (bid - 85) * 8192 + t + 256 * r;   // 16*8192 = 131072
            c1wb[n] = f2bf(c1w[n]);
        }
    } else {
        // ---- encwT[p][h] = encw[h][p] ----
        #pragma unroll
        for (int r = 0; r < 8; ++r) {
            int idx = (bid - 101) * 2048 + t + 256 * r; // 8*2048 = 16384
            int h = idx >> 7, p = idx & 127;
            encwT[p * 128 + h] = encw[idx];
        }
    }
}

// ---------------------------------------------------------------------------
// Precompute B: Weff[key][h] (1/MAX folded). Grid = 2662 WGs, 1 key each;
// u-range and p-range split across the two 128-thread halves.
// ---------------------------------------------------------------------------
__global__ __launch_bounds__(256) void k_preB(
    const float* __restrict__ W2Ft, const float* __restrict__ w1,
    const float* __restrict__ encwT, float* __restrict__ Weff)
{
    __shared__ float s_pA[2][128];
    __shared__ float s_A[128];
    const int t = threadIdx.x, key = blockIdx.x;
    const int half = t >> 7, p = t & 127;
    const int c = key / 121, rem = key % 121, X = rem / 11, Y = rem % 11;

    float acc = 0.f;
    for (int u = half * 32; u < half * 32 + 32; ++u) {
        const float* w1u = w1 + u * 550 + c * 25;
        #pragma unroll
        for (int i = 0; i < 3; ++i) {
            int xi = X - 3 * i;
            if (xi < 0 || xi > 4) continue;       // wave-uniform
            #pragma unroll
            for (int j = 0; j < 3; ++j) {
                int yj = Y - 3 * j;
                if (yj < 0 || yj > 4) continue;   // wave-uniform
                acc += w1u[xi * 5 + yj] * W2Ft[(u * 9 + i * 3 + j) * 128 + p];
            }
        }
    }
    s_pA[half][p] = acc;
    __syncthreads();
    if (half == 0) s_A[p] = (s_pA[0][p] + s_pA[1][p]) / c_maxv[c];
    __syncthreads();

    float o = 0.f;
    #pragma unroll 8
    for (int p2 = half * 64; p2 < half * 64 + 64; ++p2)
        o += encwT[p2 * 128 + p] * s_A[p2];
    s_pA[half][p] = o;
    __syncthreads();
    if (t < 128) Weff[key * 128 + t] = s_pA[0][t] + s_pA[1][t];
}

// ---------------------------------------------------------------------------
// k_hidden: decode + dedupe + hidden (done ONCE per batch) + logits.
// Grid = 2048, TB=8. Writes hb (bf16 [NB][128]) and logits to d_out.
// ---------------------------------------------------------------------------
__global__ __launch_bounds__(256) void k_hidden(
    const int* __restrict__ obs,
    const float* __restrict__ Weff, const float* __restrict__ beff,
    const float* __restrict__ Wlog, const float* __restrict__ blog,
    unsigned short* __restrict__ hb, float* __restrict__ out)
{
    __shared__ int   s_lst[TB * 32];
    __shared__ float s_hidden[TB * 128];
    __shared__ int   s_cnt[TB];

    const int tid = threadIdx.x, bid = blockIdx.x;
    const int b0 = bid * TB;

    if (tid < TB) s_cnt[tid] = 0;
    __syncthreads();

    // ---- decode + append valid tokens (pack m<<20|val<<12|key) ----
    {
        const Tok3* obs3 = (const Tok3*)obs;
        const int gtok0 = b0 * NTOK;
        #pragma unroll
        for (int k = 0; k < TB * NTOK / 256; ++k) {
            int tt = tid + 256 * k;                // tt = bb*128 + m
            Tok3 o = obs3[gtok0 + tt];
            int o0 = (o.x == 255) ? 0 : o.x;       // per-component 255 masking
            int o1 = (o.y == 255) ? 0 : o.y;
            int o2 = (o.z == 255) ? 0 : o.z;
            int x = (o0 >> 4) & 15, y = o0 & 15;
            if (x < 11 && y < 11 && o1 < 22) {
                int bb = tt >> 7, m = tt & 127;
                int pos = atomicAdd(&s_cnt[bb], 1);
                if (pos < 32)
                    s_lst[bb * 32 + pos] = (m << 20) | (o2 << 12) | (o1 * 121 + x * 11 + y);
            }
        }
    }
    __syncthreads();

    // ---- last-write-wins dedupe ----
    {
        int bb = tid >> 5, e = tid & 31;
        int n = s_cnt[bb]; if (n > 32) n = 32;
        if (e < n) {
            int p = s_lst[bb * 32 + e];
            bool dead = false;
            for (int i = 0; i < n; ++i) {
                int q = s_lst[bb * 32 + i];
                dead |= (((q ^ p) & 0xFFF) == 0) && (q > p);
            }
            if (dead) s_lst[bb * 32 + e] = p & ~0x000FF000;  // val := 0
        }
    }
    __syncthreads();

    // ---- hidden[b][h] = b_eff[h] + sum val * Weff[key][h] ----
    {
        int h = tid & 127, bg = tid >> 7;
        for (int bb = bg; bb < TB; bb += 2) {
            float acc = beff[h];
            int n = s_cnt[bb]; if (n > 32) n = 32;
            for (int i = 0; i < n; ++i) {
                int p = s_lst[bb * 32 + i];
                acc += (float)((p >> 12) & 0xFF) * Weff[(p & 0xFFF) * 128 + h];
            }
            s_hidden[bb * 128 + h] = acc;
            hb[(b0 + bb) * 128 + h] = f2bf(acc);
        }
    }
    __syncthreads();

    // ---- logits[b][o] = blog[o] + hidden[b]·Wlog[o]  (fp32) ----
    {
        const float4* s_h4 = (const float4*)s_hidden;
        const float4* wl4  = (const float4*)Wlog;
        int bl = tid >> 5, o = tid & 31;
        if (o < NLOG) {
            float acc = blog[o];
            #pragma unroll
            for (int hq = 0; hq < 32; ++hq) {
                float4 hv = s_h4[bl * 32 + hq];
                float4 wl = wl4[o * 32 + hq];
                acc += wl.x * hv.x + wl.y * hv.y + wl.z * hv.z + wl.w * hv.w;
            }
            out[(b0 + bl) * NLOG + o] = acc;
        }
    }
}

// ---------------------------------------------------------------------------
// k_gemm: value partials. Grid = 256 M-tiles x 4 N-slices = 1024 WGs.
// Per WG: M=64 rows, N=256 j, K=128. 4 waves: wave w owns the 64-j slice
// [nb*256 + w*64 ..). A staged in LDS (pitch 136); B from L2-resident c1wb.
// ---------------------------------------------------------------------------
__global__ __launch_bounds__(256) void k_gemm(
    const unsigned short* __restrict__ hb,
    const unsigned short* __restrict__ c1wb, const float* __restrict__ c1b,
    const float* __restrict__ vw, float* __restrict__ vpartial)
{
    __shared__ unsigned short sA[64 * 136];     // 17.4 KB
    __shared__ float s_vp[4][64];

    const int tid = threadIdx.x, bid = blockIdx.x;
    const int nb = bid & 3;                     // N-slice (256 j)
    const int b0 = (bid >> 2) * 64;             // M-tile (64 rows)

    // stage A: 64 rows x 128 k bf16 (1024 x short8)
    {
        const short8* hb8 = (const short8*)(hb + b0 * 128);
        #pragma unroll
        for (int i = 0; i < 4; ++i) {
            int idx = tid + 256 * i;            // 1024
            int r = idx >> 4, c = idx & 15;
            *(short8*)&sA[r * 136 + c * 8] = hb8[idx];
        }
    }
    __syncthreads();

    const int lane = tid & 63, w = tid >> 6;
    const int lm = lane & 15, quad = lane >> 4;

    floatx4 acc[4][4];                          // [mt][nt]
    #pragma unroll
    for (int mt = 0; mt < 4; ++mt)
        #pragma unroll
        for (int nt = 0; nt < 4; ++nt)
            acc[mt][nt] = (floatx4){0.f, 0.f, 0.f, 0.f};

    #pragma unroll
    for (int ks = 0; ks < 4; ++ks) {
        short8 af[4];
        #pragma unroll
        for (int mt = 0; mt < 4; ++mt)
            af[mt] = *(const short8*)&sA[(mt * 16 + lm) * 136 + ks * 32 + quad * 8];
        #pragma unroll
        for (int nt = 0; nt < 4; ++nt) {
            int j = nb * 256 + w * 64 + nt * 16 + lm;
            short8 bf = *(const short8*)&c1wb[j * 128 + ks * 32 + quad * 8];
            #pragma unroll
            for (int mt = 0; mt < 4; ++mt)
                acc[mt][nt] = __builtin_amdgcn_mfma_f32_16x16x32_bf16(af[mt], bf, acc[mt][nt], 0, 0, 0);
        }
    }

    // epilogue: vpart[row] = sum_j tanh(acc + b_j) * vw_j over this wave's 64 j
    #pragma unroll
    for (int mt = 0; mt < 4; ++mt) {
        float vp[4] = {0.f, 0.f, 0.f, 0.f};
        #pragma unroll
        for (int nt = 0; nt < 4; ++nt) {
            int j = nb * 256 + w * 64 + nt * 16 + lm;   // lm = D col
            float bj = c1b[j], wj = vw[j];
            #pragma unroll
            for (int r = 0; r < 4; ++r)                 // row = quad*4+r
                vp[r] += tanh_fast(acc[mt][nt][r] + bj) * wj;
        }
        #pragma unroll
        for (int off = 1; off <= 8; off <<= 1)          // reduce 16 cols
            #pragma unroll
            for (int r = 0; r < 4; ++r)
                vp[r] += __shfl_xor(vp[r], off, 64);
        if (lm == 0) {
            #pragma unroll
            for (int r = 0; r < 4; ++r)
                s_vp[w][mt * 16 + quad * 4 + r] = vp[r];
        }
    }
    __syncthreads();
    if (tid < 64)
        vpartial[nb * NB + b0 + tid] =
            s_vp[0][tid] + s_vp[1][tid] + s_vp[2][tid] + s_vp[3][tid];
}

// ---------------------------------------------------------------------------
// Final: value[b] = vb + sum over 4 N-slice partials. Grid = 64 WGs.
// ---------------------------------------------------------------------------
__global__ __launch_bounds__(256) void k_fin(
    const float* __restrict__ vpartial, const float* __restrict__ vb,
    float* __restrict__ out)
{
    int i = blockIdx.x * 256 + threadIdx.x;        // 64*256 = 16384 exact
    out[NB * NLOG + i] = vb[0] + vpartial[i] + vpartial[NB + i]
                       + vpartial[2 * NB + i] + vpartial[3 * NB + i];
}

// ---------------------------------------------------------------------------
extern "C" void kernel_launch(void* const* d_in, const int* in_sizes, int n_in,
                              void* d_out, int out_size, void* d_ws, size_t ws_size,
                              hipStream_t stream)
{
    const int*   obs  = (const int*)  d_in[0];
    const float* w1   = (const float*)d_in[1];
    const float* b1   = (const float*)d_in[2];
    const float* w2   = (const float*)d_in[3];
    const float* b2   = (const float*)d_in[4];
    const float* fc1w = (const float*)d_in[5];
    const float* fc1b = (const float*)d_in[6];
    const float* encw = (const float*)d_in[7];
    const float* encb = (const float*)d_in[8];
    const float* c1w  = (const float*)d_in[9];
    const float* c1b  = (const float*)d_in[10];
    const float* vw   = (const float*)d_in[11];
    const float* vb   = (const float*)d_in[12];
    const float* a1w  = (const float*)d_in[13];
    const float* a1b  = (const float*)d_in[14];
    const float* aemb = (const float*)d_in[15];
    const float* h0w  = (const float*)d_in[16];
    const float* h0b  = (const float*)d_in[17];
    const float* h1w  = (const float*)d_in[18];
    const float* h1b  = (const float*)d_in[19];

    float* W     = (float*)d_ws;
    float* W2Ft  = W;                 // 73728   (576 x 128)
    float* encwT = W + 73728;         // 16384
    float* beff  = W + 90112;         // 128
    float* blog  = W + 90240;         // 32
    float* Wlog  = W + 90272;         // 2432
    float* Weff  = W + 92704;         // 340736
    unsigned short* c1wb = (unsigned short*)(W + 433440);  // 131072 us (65536 f)
    unsigned short* hb   = (unsigned short*)(W + 498976);  // 2097152 us (1048576 f)
    float* vpart = W + 1547552;       // 65536 (4 x NB)    total ~6.45 MB

    hipLaunchKernelGGL(k_preA, dim3(109), dim3(256), 0, stream,
                       w1, b1, w2, b2, fc1w, fc1b, encw, encb, a1w, a1b, aemb,
                       h0w, h0b, h1w, h1b, c1w,
                       W2Ft, encwT, beff, blog, Wlog, c1wb);
    hipLaunchKernelGGL(k_preB, dim3(NKEY), dim3(256), 0, stream,
                       W2Ft, w1, encwT, Weff);
    hipLaunchKernelGGL(k_hidden, dim3(NB / TB), dim3(256), 0, stream,
                       obs, Weff, beff, Wlog, blog, hb, (float*)d_out);
    hipLaunchKernelGGL(k_gemm, dim3(1024), dim3(256), 0, stream,
                       hb, c1wb, c1b, vw, vpart);
    hipLaunchKernelGGL(k_fin, dim3(64), dim3(256), 0, stream,
                       vpart, vb, (float*)d_out);
}